// Round 1
// baseline (428.702 us; speedup 1.0000x reference)
//
#include <hip/hip_runtime.h>

#define EPSV 1e-5f

typedef __bf16 bf16x8 __attribute__((ext_vector_type(8)));
typedef float f32x4 __attribute__((ext_vector_type(4)));
typedef unsigned int u32x4 __attribute__((ext_vector_type(4)));
typedef unsigned short u16x4 __attribute__((ext_vector_type(4)));

__device__ __forceinline__ unsigned short f2bf(float f) {
  return __builtin_bit_cast(unsigned short, static_cast<__bf16>(f));
}

constexpr int Himg = 112, Wimg = 112, HWp = Himg * Wimg;  // 12544

// ---------------------------------------------------------------------------
// prep_misc: w[co][ci][3][3] f32 -> wT[tap][co][ci] bf16 ; BN1/BN2 scale/shift
// ---------------------------------------------------------------------------
__global__ __launch_bounds__(256) void prep_misc(
    const float* __restrict__ w1, const float* __restrict__ w2,
    const float* __restrict__ g1, const float* __restrict__ b1,
    const float* __restrict__ m1, const float* __restrict__ v1,
    const float* __restrict__ g2, const float* __restrict__ b2,
    const float* __restrict__ m2, const float* __restrict__ v2,
    unsigned short* __restrict__ wt1, unsigned short* __restrict__ wt2,
    float* __restrict__ prm)
{
  int id = blockIdx.x * 256 + threadIdx.x;
  for (int i = id; i < 9 * 64 * 64; i += gridDim.x * 256) {
    int t   = i >> 12;          // tap
    int rem = i & 4095;
    int co  = rem >> 6, ci = rem & 63;
    int kh  = t / 3, kw = t - kh * 3;
    int src = ((co * 64 + ci) * 3 + kh) * 3 + kw;
    wt1[i] = f2bf(w1[src]);
    wt2[i] = f2bf(w2[src]);
  }
  if (id < 64) {
    float s1 = g1[id] * rsqrtf(v1[id] + EPSV);
    prm[id]      = s1;
    prm[64 + id] = b1[id] - m1[id] * s1;
    float s2 = g2[id] * rsqrtf(v2[id] + EPSV);
    prm[128 + id] = s2;
    prm[192 + id] = b2[id] - m2[id] * s2;
  }
}

// ---------------------------------------------------------------------------
// prep_x0: x NCHW f32 -> x0 = BN0(x) as NHWC bf16 (pixel-major, ci contiguous)
// one block per (n,h) row; LDS transpose for coalescing on both sides
// ---------------------------------------------------------------------------
__global__ __launch_bounds__(256) void prep_x0(
    const float* __restrict__ x,
    const float* __restrict__ g0, const float* __restrict__ b0,
    const float* __restrict__ m0, const float* __restrict__ v0,
    unsigned short* __restrict__ x0)
{
  __shared__ float sc[64];
  __shared__ float sh[64];
  __shared__ float tile[64][113];
  const int t = threadIdx.x;
  const int bid = blockIdx.x;          // n*112 + h
  const int n = bid / 112, h = bid - n * 112;
  if (t < 64) {
    float s = g0[t] * rsqrtf(v0[t] + EPSV);
    sc[t] = s;
    sh[t] = b0[t] - m0[t] * s;
  }
  __syncthreads();
  const float* xp = x + (size_t)n * 64 * HWp + h * Wimg;
  for (int i = t; i < 64 * Wimg; i += 256) {
    int c = i / Wimg, w = i - c * Wimg;
    tile[c][w] = xp[(size_t)c * HWp + w] * sc[c] + sh[c];
  }
  __syncthreads();
  unsigned short* op = x0 + (size_t)bid * Wimg * 64;
  for (int i = t * 4; i < Wimg * 64; i += 1024) {
    int w = i >> 6, c = i & 63;       // i multiple of 4 -> c in {0,4,...,60}
    u16x4 u;
    u[0] = f2bf(tile[c + 0][w]);
    u[1] = f2bf(tile[c + 1][w]);
    u[2] = f2bf(tile[c + 2][w]);
    u[3] = f2bf(tile[c + 3][w]);
    *reinterpret_cast<u16x4*>(op + i) = u;
  }
}

// ---------------------------------------------------------------------------
// conv3x3k<STAGE>: implicit-GEMM 3x3 conv via mfma_f32_16x16x32_bf16.
//   block: 256 thr = 4 waves, output tile 16x16 pixels x 64 couts
//   wave wv: rows 4wv..4wv+3 (pfrag = one row of 16 w), all 64 couts (4 cofrags)
//   orientation: A = weights [co][ci], B = patch [ci][pixel] -> D[co][pixel]
//   LDS: patch 18x18x64 bf16 (41472 B, XOR-swizzled 16B chunks) +
//        2 x 8 KB per-tap weight double-buffer  => 57856 B -> 2 blocks/CU
//   STAGE 1: epilogue BN1+PReLU1 -> y1 bf16 NHWC
//   STAGE 2: epilogue BN2 + residual(x NCHW f32) + PReLU2 -> out f32 NCHW
// ---------------------------------------------------------------------------
template <int STAGE>
__global__ __launch_bounds__(256, 2) void conv3x3k(
    const unsigned short* __restrict__ src,   // bf16 NHWC [P][64]
    const unsigned short* __restrict__ wT,    // bf16 [9][64][64]
    const float* __restrict__ scale, const float* __restrict__ shift,
    const float* __restrict__ aP,
    unsigned short* __restrict__ dstb,        // STAGE 1 out
    float* __restrict__ dstf,                 // STAGE 2 out
    const float* __restrict__ resid)          // STAGE 2 residual
{
  __shared__ __align__(16) unsigned char lds[41472 + 2 * 8192];
  const int t = threadIdx.x;
  const int bid = blockIdx.x;
  const int n  = bid / 49;
  const int r2 = bid - n * 49;
  const int hb = r2 / 7, wb = r2 - hb * 7;
  const int h0 = hb * 16, w0 = wb * 16;
  const size_t ibase = (size_t)n * HWp;

  // ---- stage input patch (18x18 pixels x 64 ci, zero halo) ----
  for (int i = t; i < 18 * 18 * 8; i += 256) {
    int q = i >> 3, k = i & 7;                 // q = patch pixel, k = 16B chunk
    int pr = q / 18, pc = q - pr * 18;
    int hh = h0 - 1 + pr, ww = w0 - 1 + pc;
    u32x4 val = {0u, 0u, 0u, 0u};
    if ((unsigned)hh < 112u && (unsigned)ww < 112u) {
      val = *reinterpret_cast<const u32x4*>(src + (ibase + hh * Wimg + ww) * 64 + k * 8);
    }
    *reinterpret_cast<u32x4*>(&lds[q * 128 + ((k ^ (q & 7)) << 4)]) = val;
  }
  // ---- stage tap-0 weights ----
  {
    int i = t;
#pragma unroll
    for (int it = 0; it < 2; ++it, i += 256) {
      int row = i >> 3, k = i & 7;
      u32x4 v = *reinterpret_cast<const u32x4*>(wT + i * 8);
      *reinterpret_cast<u32x4*>(&lds[41472 + row * 128 + ((k ^ (row & 7)) << 4)]) = v;
    }
  }
  __syncthreads();

  const int l = t & 63, wv = t >> 6;
  const int lo = l & 15, grp = l >> 4;

  f32x4 acc[4][4];
#pragma unroll
  for (int c = 0; c < 4; ++c)
#pragma unroll
    for (int p = 0; p < 4; ++p) {
      f32x4 z = {0.f, 0.f, 0.f, 0.f};
      acc[c][p] = z;
    }

#pragma unroll
  for (int tap = 0; tap < 9; ++tap) {
    const int dh = tap / 3, dw = tap - (tap / 3) * 3;
    u32x4 pre0, pre1;
    if (tap < 8) {  // T14: issue next-tap weight loads early
      const unsigned short* wsrc = wT + (tap + 1) * 4096;
      pre0 = *reinterpret_cast<const u32x4*>(wsrc + t * 8);
      pre1 = *reinterpret_cast<const u32x4*>(wsrc + (t + 256) * 8);
    }
    const int wbase = 41472 + (tap & 1) * 8192;
#pragma unroll
    for (int ks = 0; ks < 2; ++ks) {
      const int chunk = ks * 4 + grp;
      bf16x8 wf[4], pf[4];
#pragma unroll
      for (int c = 0; c < 4; ++c) {
        int row = c * 16 + lo;
        wf[c] = *reinterpret_cast<const bf16x8*>(
            &lds[wbase + row * 128 + ((chunk ^ (row & 7)) << 4)]);
      }
#pragma unroll
      for (int p = 0; p < 4; ++p) {
        int q = (4 * wv + p + dh) * 18 + lo + dw;
        pf[p] = *reinterpret_cast<const bf16x8*>(
            &lds[q * 128 + ((chunk ^ (q & 7)) << 4)]);
      }
#pragma unroll
      for (int c = 0; c < 4; ++c)
#pragma unroll
        for (int p = 0; p < 4; ++p)
          acc[c][p] = __builtin_amdgcn_mfma_f32_16x16x32_bf16(wf[c], pf[p], acc[c][p], 0, 0, 0);
    }
    if (tap < 8) {  // write-late into the other buffer
      const int wnx = 41472 + ((tap + 1) & 1) * 8192;
      int row0 = t >> 3, k0 = t & 7;
      *reinterpret_cast<u32x4*>(&lds[wnx + row0 * 128 + ((k0 ^ (row0 & 7)) << 4)]) = pre0;
      int i1 = t + 256;
      int row1 = i1 >> 3, k1 = i1 & 7;
      *reinterpret_cast<u32x4*>(&lds[wnx + row1 * 128 + ((k1 ^ (row1 & 7)) << 4)]) = pre1;
    }
    if (tap < 8) __syncthreads();
  }

  // ---- epilogue ----
  // D layout (16x16x32): col = lane&15 -> pixel ; row = (lane>>4)*4 + reg -> co
#pragma unroll
  for (int c = 0; c < 4; ++c) {
    const int co0 = c * 16 + grp * 4;
    float s_[4], h_[4], a_[4];
#pragma unroll
    for (int j = 0; j < 4; ++j) {
      s_[j] = scale[co0 + j];
      h_[j] = shift[co0 + j];
      a_[j] = aP[co0 + j];
    }
#pragma unroll
    for (int p = 0; p < 4; ++p) {
      const int hh = h0 + 4 * wv + p;
      const int ww = w0 + lo;
      f32x4 v = acc[c][p];
      if (STAGE == 1) {
        u16x4 u;
#pragma unroll
        for (int j = 0; j < 4; ++j) {
          float vv = v[j] * s_[j] + h_[j];
          vv = vv >= 0.f ? vv : vv * a_[j];
          u[j] = f2bf(vv);
        }
        *reinterpret_cast<u16x4*>(dstb + (ibase + hh * Wimg + ww) * 64 + co0) = u;
      } else {
#pragma unroll
        for (int j = 0; j < 4; ++j) {
          size_t oidx = ((size_t)(n * 64 + co0 + j) * Himg + hh) * Wimg + ww;
          float vv = v[j] * s_[j] + h_[j] + resid[oidx];
          vv = vv >= 0.f ? vv : vv * a_[j];
          dstf[oidx] = vv;
        }
      }
    }
  }
}

// ---------------------------------------------------------------------------
// launch: prep_misc ; prep_x0 ; conv1 ; conv2   (all on `stream`)
// scratch map:
//   d_out[0 .. 102,760,448)          : x0 bf16 NHWC (dead before conv2 writes)
//   d_ws [0 .. 102,760,448)          : y1 bf16 NHWC
//   d_ws [+0 .. +73,728)             : wt1 bf16
//   d_ws [+73,728 .. +147,456)       : wt2 bf16
//   d_ws [+147,456 .. +148,480)      : prm f32 (s1,sh1,s2,sh2) x 64
//   requires ws_size >= 102,908,928 B (~98.2 MiB)
// ---------------------------------------------------------------------------
extern "C" void kernel_launch(void* const* d_in, const int* in_sizes, int n_in,
                              void* d_out, int out_size, void* d_ws, size_t ws_size,
                              hipStream_t stream)
{
  const float* x  = (const float*)d_in[0];
  const float* w1 = (const float*)d_in[1];
  const float* w2 = (const float*)d_in[2];
  const float* g0 = (const float*)d_in[3];
  const float* b0 = (const float*)d_in[4];
  const float* m0 = (const float*)d_in[5];
  const float* v0 = (const float*)d_in[6];
  const float* g1 = (const float*)d_in[7];
  const float* b1 = (const float*)d_in[8];
  const float* m1 = (const float*)d_in[9];
  const float* v1 = (const float*)d_in[10];
  const float* g2 = (const float*)d_in[11];
  const float* b2 = (const float*)d_in[12];
  const float* m2 = (const float*)d_in[13];
  const float* v2 = (const float*)d_in[14];
  const float* a1 = (const float*)d_in[15];
  const float* a2 = (const float*)d_in[16];

  unsigned short* x0 = (unsigned short*)d_out;
  unsigned char* wsb = (unsigned char*)d_ws;
  unsigned short* y1  = (unsigned short*)wsb;
  unsigned short* wt1 = (unsigned short*)(wsb + 102760448);
  unsigned short* wt2 = (unsigned short*)(wsb + 102760448 + 73728);
  float* prm          = (float*)(wsb + 102760448 + 2 * 73728);

  prep_misc<<<16, 256, 0, stream>>>(w1, w2, g1, b1, m1, v1, g2, b2, m2, v2, wt1, wt2, prm);
  prep_x0<<<64 * 112, 256, 0, stream>>>(x, g0, b0, m0, v0, x0);
  conv3x3k<1><<<3136, 256, 0, stream>>>(x0, wt1, prm, prm + 64, a1, y1, nullptr, nullptr);
  conv3x3k<2><<<3136, 256, 0, stream>>>(y1, wt2, prm + 128, prm + 192, a2, nullptr, (float*)d_out, x);
}